// Round 14
// baseline (1075.561 us; speedup 1.0000x reference)
//
#include <hip/hip_runtime.h>
#include <math.h>

// ---------------------------------------------------------------------------
// QuantumSuperpositionAttention  (B=1, N=1024, DIM=512, H=8, DH=64, k=102)
//
// Identities:
//  * phase MLP is dead code: |alpha * e^{i phi}|^2 == |alpha|^2
//  * cayley(M): A = 0.02*((Mre - Mre^T) + i(Mim + Mim^T));
//    W = (I + 2A + A^2)(I - A^2)^{-1};  B = I - A^2 Hermitian PD, spec [1,5).
//  * inv(B): deg-4 minimax init (PS form, 3 GEMMs) + 2 NS -> rho ~ 7e-8 <
//    fp32 GEMM floor. 8 z=4 GEMMs total.
//  * ACCURACY RULES (R7/R9): W error must sit AT the fp32 floor; never change
//    summation ORDER in the Wq/Wk/Q/K/scores chain. (Floor-scale W
//    REALIZATION changes are safe: R6/R8/R12/R13 all exactly 1 bf16 ulp.)
//  * D_OUT BOUNDS RULE (R10/R11): d_out holds exactly out_size floats;
//    ALL d_out writes go through the bounded copy_out kernel.
//  * TRI LESSON (R13): triangular tile-skipping saves no time — 288 blocks
//    still leave 2 blocks on some CUs = unchanged critical path. Reverted.
//
// R14: cgemm A-operand moved LDS -> direct global b128 register loads
// (broadcast lanes coalesce; ~4us L2 traffic). LDS pipe now carries Bs only:
// cap 64/(4*22) ~ 72% VALU (was 55%, As+Bs ~29 cyc/k). Bitwise-identical
// operand values and FMA order.
// R12: BK=32; R8: deg-4+2NS; R6: 32x64 tile; R5: z=4 batch; R3: pool.
// ---------------------------------------------------------------------------

#define PLANE   262144      // 512*512
#define CMAT    524288      // floats per complex 512x512 (2 MB)
#define PPLANE  524288      // 1024*512
#define CPROJ   1048576     // floats per complex 1024x512 (4 MB)
#define KTOP    102

// Wall(4*CMAT) + RS(8192) + R = max(phaseA 24*CMAT, phaseB 4*CPROJ + 8M B2)
#define R_FLOATS 12582912
#define POOL_FLOATS (4*CMAT + 8192 + R_FLOATS)
__device__ __attribute__((aligned(256))) float g_pool[POOL_FLOATS];

// ---------------------------------------------------------------------------
// Complex planar GEMM: C = (use_d ? dcoef*D - A*B : A*B). Batched via z.
// 32x64 C-tile / 256 threads / 2x4 complex microtile / BK=32.
// Grid: (N/64, M/32, batch). K % 32 == 0. All C targets are pool (16B-ok).
// A-operand: direct global float4 loads (2 rows/thread, broadcast-coalesced);
// B-operand: staged in LDS (8x reuse across the 32 tile rows).
// ---------------------------------------------------------------------------
__launch_bounds__(256)
__global__ void cgemm_kernel(
    const float* __restrict__ Are, const float* __restrict__ Aim, int sA,
    const float* __restrict__ Bre, const float* __restrict__ Bim, int sB,
    const float* __restrict__ Dre, const float* __restrict__ Dim, int sD,
    float* __restrict__ Cre, float* __restrict__ Cim, int sC,
    int M, int N, int Kd, float dcoef, int use_d)
{
    __shared__ float Bs_re[32][68], Bs_im[32][68];
    const int b = blockIdx.z;
    Are += (size_t)b * sA; Aim += (size_t)b * sA;
    Bre += (size_t)b * sB; Bim += (size_t)b * sB;
    Dre += (size_t)b * sD; Dim += (size_t)b * sD;
    Cre += (size_t)b * sC; Cim += (size_t)b * sC;
    const int tid = threadIdx.x;
    const int bm = blockIdx.y * 32, bn = blockIdx.x * 64;
    const int tm = (tid >> 4) << 1;      // 0..30 (2 rows)
    const int tn = (tid & 15) << 2;      // 0..60 (4 cols)
    const int lkB = tid >> 4;            // 0..15 (rows lkB and lkB+16)
    const int lnB = (tid & 15) << 2;     // 0..60
    float cr[2][4] = {{0.f}}, ci[2][4] = {{0.f}};
    const float* pA0r = Are + (size_t)(bm + tm) * Kd;
    const float* pA0i = Aim + (size_t)(bm + tm) * Kd;
    const float* pA1r = Are + (size_t)(bm + tm + 1) * Kd;
    const float* pA1i = Aim + (size_t)(bm + tm + 1) * Kd;
    const float* pBre = Bre + (size_t)lkB * N + bn + lnB;
    const float* pBim = Bim + (size_t)lkB * N + bn + lnB;
    for (int k0 = 0; k0 < Kd; k0 += 32) {
        const float4 br0 = *(const float4*)(pBre + (size_t)k0 * N);
        const float4 bi0 = *(const float4*)(pBim + (size_t)k0 * N);
        const float4 br1 = *(const float4*)(pBre + (size_t)(k0 + 16) * N);
        const float4 bi1 = *(const float4*)(pBim + (size_t)(k0 + 16) * N);
        __syncthreads();
        *(float4*)&Bs_re[lkB][lnB] = br0;
        *(float4*)&Bs_im[lkB][lnB] = bi0;
        *(float4*)&Bs_re[lkB+16][lnB] = br1;
        *(float4*)&Bs_im[lkB+16][lnB] = bi1;
        __syncthreads();
        #pragma unroll
        for (int kk = 0; kk < 32; kk += 4) {
            const float4 a0r = *(const float4*)(pA0r + k0 + kk);
            const float4 a0i = *(const float4*)(pA0i + k0 + kk);
            const float4 a1r = *(const float4*)(pA1r + k0 + kk);
            const float4 a1i = *(const float4*)(pA1i + k0 + kk);
            const float* a0rp = (const float*)&a0r;
            const float* a0ip = (const float*)&a0i;
            const float* a1rp = (const float*)&a1r;
            const float* a1ip = (const float*)&a1i;
            #pragma unroll
            for (int dk = 0; dk < 4; ++dk) {
                const int k = kk + dk;
                const float4 yr = *(const float4*)&Bs_re[k][tn];
                const float4 yi = *(const float4*)&Bs_im[k][tn];
                const float axr[2] = {a0rp[dk], a1rp[dk]};
                const float axi[2] = {a0ip[dk], a1ip[dk]};
                const float byr[4] = {yr.x, yr.y, yr.z, yr.w};
                const float byi[4] = {yi.x, yi.y, yi.z, yi.w};
                #pragma unroll
                for (int i = 0; i < 2; ++i) {
                    #pragma unroll
                    for (int j = 0; j < 4; ++j) {
                        cr[i][j] += axr[i]*byr[j] - axi[i]*byi[j];
                        ci[i][j] += axr[i]*byi[j] + axi[i]*byr[j];
                    }
                }
            }
        }
    }
    #pragma unroll
    for (int i = 0; i < 2; ++i) {
        const size_t idx = (size_t)(bm + tm + i) * N + bn + tn;
        float4 vr = make_float4(cr[i][0], cr[i][1], cr[i][2], cr[i][3]);
        float4 vi = make_float4(ci[i][0], ci[i][1], ci[i][2], ci[i][3]);
        if (use_d) {
            const float4 dr4 = *(const float4*)(Dre + idx);
            const float4 di4 = *(const float4*)(Dim + idx);
            vr.x = dcoef*dr4.x - vr.x; vr.y = dcoef*dr4.y - vr.y;
            vr.z = dcoef*dr4.z - vr.z; vr.w = dcoef*dr4.w - vr.w;
            vi.x = dcoef*di4.x - vi.x; vi.y = dcoef*di4.y - vi.y;
            vi.z = dcoef*di4.z - vi.z; vi.w = dcoef*di4.w - vi.w;
        }
        *(float4*)(Cre + idx) = vr;
        *(float4*)(Cim + idx) = vi;
    }
}

// A = 0.02*((Mre - Mre^T) + i(Mim + Mim^T)) for all 4 weights (blockIdx.y).
__launch_bounds__(256)
__global__ void build_A_kernel(const float* __restrict__ W0re, const float* __restrict__ W0im,
                               const float* __restrict__ W1re, const float* __restrict__ W1im,
                               const float* __restrict__ W2re, const float* __restrict__ W2im,
                               const float* __restrict__ W3re, const float* __restrict__ W3im,
                               int aoff)
{
    float* Aout = g_pool + aoff;
    const int w = blockIdx.y;
    const float* Mre; const float* Mim;
    if      (w == 0) { Mre = W0re; Mim = W0im; }
    else if (w == 1) { Mre = W1re; Mim = W1im; }
    else if (w == 2) { Mre = W2re; Mim = W2im; }
    else             { Mre = W3re; Mim = W3im; }
    const int idx = blockIdx.x * 256 + threadIdx.x;   // < 262144
    const int i = idx >> 9, j = idx & 511;
    float* Are = Aout + (size_t)w * CMAT;
    float* Aim = Are + PLANE;
    Are[idx] = 0.02f * (Mre[i*512 + j] - Mre[j*512 + i]);
    Aim[idx] = 0.02f * (Mim[i*512 + j] + Mim[j*512 + i]);
}

// U = 5.5*S + 0.5*S2  (flat over both planes)
__launch_bounds__(256)
__global__ void u_kernel(const float* __restrict__ S, const float* __restrict__ S2,
                         float* __restrict__ U)
{
    const int w = blockIdx.y;
    const int idx = blockIdx.x * 256 + threadIdx.x;   // < CMAT
    const size_t off = (size_t)w * CMAT;
    U[off + idx] = 5.5f * S[off + idx] + 0.5f * S2[off + idx];
}

// X0 = (60.5 I + 48 S + 23 S2 + V)/61.5, V = S2*(5.5 S + 0.5 S2)
__launch_bounds__(256)
__global__ void x0deg4_kernel(const float* __restrict__ S, const float* __restrict__ S2,
                              const float* __restrict__ V, float* __restrict__ X)
{
    const float inv = 1.0f/61.5f;
    const int w = blockIdx.y;
    const int idx = blockIdx.x * 256 + threadIdx.x;   // < PLANE
    const int i = idx >> 9, j = idx & 511;
    const size_t off = (size_t)w * CMAT;
    const float* Sre = S + off;   const float* Sim = Sre + PLANE;
    const float* S2re = S2 + off; const float* S2im = S2re + PLANE;
    const float* Vre = V + off;   const float* Vim = Vre + PLANE;
    float* Xre = X + off; float* Xim = Xre + PLANE;
    const float diag = (i == j) ? 60.5f : 0.0f;
    Xre[idx] = (diag + 48.f * Sre[idx] + 23.f * S2re[idx] + Vre[idx]) * inv;
    Xim[idx] = (       48.f * Sim[idx] + 23.f * S2im[idx] + Vim[idx]) * inv;
}

// P = I + 2A + S
__launch_bounds__(256)
__global__ void buildP_kernel(const float* __restrict__ A, const float* __restrict__ S,
                              float* __restrict__ P)
{
    const int w = blockIdx.y;
    const int idx = blockIdx.x * 256 + threadIdx.x;
    const int i = idx >> 9, j = idx & 511;
    const float* Are = A + (size_t)w * CMAT; const float* Aim = Are + PLANE;
    const float* Sre = S + (size_t)w * CMAT; const float* Sim = Sre + PLANE;
    float* Pre = P + (size_t)w * CMAT; float* Pim = Pre + PLANE;
    const float d = (i == j) ? 1.0f : 0.0f;
    Pre[idx] = d + 2.0f * Are[idx] + Sre[idx];
    Pim[idx] = 2.0f * Aim[idx] + Sim[idx];
}

__launch_bounds__(256)
__global__ void zero_kernel(float* __restrict__ p, int n)
{
    const int i = blockIdx.x * 256 + threadIdx.x;
    if (i < n) p[i] = 0.f;
}

// All heads: b2[h,n,s] = |conj(Q[n,h,:]) . K[s,h,:]|^2 * SCALE^2, + row sums.
__launch_bounds__(256)
__global__ void scores_kernel(const float* __restrict__ Qre, const float* __restrict__ Qim,
                              const float* __restrict__ Kre, const float* __restrict__ Kim,
                              float* __restrict__ B2, float* __restrict__ RS)
{
    __shared__ float Qs_re[16][68], Qs_im[16][68], Ks_re[16][68], Ks_im[16][68];
    __shared__ float rs[64];
    const int h = blockIdx.z;
    const int bm = blockIdx.y * 64, bn = blockIdx.x * 64;
    const int tid = threadIdx.x;
    const int tm = (tid >> 4) << 2, tn = (tid & 15) << 2;
    const int lm = tid >> 2, lk = (tid & 3) << 2;
    float dr[4][4] = {{0.f}}, di[4][4] = {{0.f}};
    for (int k0 = 0; k0 < 64; k0 += 16) {
        const float4 qr = *(const float4*)(Qre + (size_t)(bm+lm)*512 + h*64 + k0 + lk);
        const float4 qi = *(const float4*)(Qim + (size_t)(bm+lm)*512 + h*64 + k0 + lk);
        const float4 kr = *(const float4*)(Kre + (size_t)(bn+lm)*512 + h*64 + k0 + lk);
        const float4 ki = *(const float4*)(Kim + (size_t)(bn+lm)*512 + h*64 + k0 + lk);
        __syncthreads();
        Qs_re[lk+0][lm]=qr.x; Qs_re[lk+1][lm]=qr.y; Qs_re[lk+2][lm]=qr.z; Qs_re[lk+3][lm]=qr.w;
        Qs_im[lk+0][lm]=qi.x; Qs_im[lk+1][lm]=qi.y; Qs_im[lk+2][lm]=qi.z; Qs_im[lk+3][lm]=qi.w;
        Ks_re[lk+0][lm]=kr.x; Ks_re[lk+1][lm]=kr.y; Ks_re[lk+2][lm]=kr.z; Ks_re[lk+3][lm]=kr.w;
        Ks_im[lk+0][lm]=ki.x; Ks_im[lk+1][lm]=ki.y; Ks_im[lk+2][lm]=ki.z; Ks_im[lk+3][lm]=ki.w;
        __syncthreads();
        #pragma unroll
        for (int k = 0; k < 16; ++k) {
            const float4 xr = *(const float4*)&Qs_re[k][tm];
            const float4 xi = *(const float4*)&Qs_im[k][tm];
            const float4 yr = *(const float4*)&Ks_re[k][tn];
            const float4 yi = *(const float4*)&Ks_im[k][tn];
            const float axr[4] = {xr.x, xr.y, xr.z, xr.w};
            const float axi[4] = {xi.x, xi.y, xi.z, xi.w};
            const float byr[4] = {yr.x, yr.y, yr.z, yr.w};
            const float byi[4] = {yi.x, yi.y, yi.z, yi.w};
            #pragma unroll
            for (int i = 0; i < 4; ++i) {
                #pragma unroll
                for (int j = 0; j < 4; ++j) {
                    dr[i][j] += axr[i]*byr[j] + axi[i]*byi[j];   // re(conj(q)*k)
                    di[i][j] += axr[i]*byi[j] - axi[i]*byr[j];   // im(conj(q)*k)
                }
            }
        }
    }
    if (tid < 64) rs[tid] = 0.f;
    __syncthreads();
    float rpart[4] = {0.f, 0.f, 0.f, 0.f};
    #pragma unroll
    for (int i = 0; i < 4; ++i) {
        #pragma unroll
        for (int j = 0; j < 4; ++j) {
            const float b2v = (dr[i][j]*dr[i][j] + di[i][j]*di[i][j]) * 0.015625f;
            B2[(size_t)h*1048576 + (size_t)(bm+tm+i)*1024 + (bn+tn+j)] = b2v;
            rpart[i] += b2v;
        }
    }
    #pragma unroll
    for (int i = 0; i < 4; ++i) atomicAdd(&rs[tm+i], rpart[i]);
    __syncthreads();
    if (tid < 64) atomicAdd(&RS[h*1024 + bm + tid], rs[tid]);
}

// Per (h,n) row: exact top-102 radix select, softmax, weighted V gather.
__launch_bounds__(256)
__global__ void select_kernel(const float* __restrict__ B2, const float* __restrict__ RS,
                              const float* __restrict__ Vre, const float* __restrict__ Vim,
                              float* __restrict__ AOre, float* __restrict__ AOim)
{
    __shared__ float sv[1024];
    __shared__ unsigned int hist[256];
    __shared__ int ssum[256];
    __shared__ unsigned int sc[4];
    __shared__ float sel_v[104];
    __shared__ int sel_i[104];
    __shared__ float sel_w[104];
    __shared__ float rbuf[256];
    const int bid = blockIdx.x;
    const int h = bid >> 10, n = bid & 1023;
    const int tid = threadIdx.x;
    const float* row = B2 + (size_t)h * 1048576 + (size_t)n * 1024;
    #pragma unroll
    for (int e = 0; e < 4; ++e) sv[tid + 256*e] = row[tid + 256*e];
    if (tid == 0) sc[2] = 0u;
    __syncthreads();

    unsigned prefix = 0u, pmask = 0u;
    int krem = KTOP;
    for (int pass = 0; pass < 4; ++pass) {
        const int shift = 24 - 8 * pass;
        hist[tid] = 0u;
        __syncthreads();
        #pragma unroll
        for (int e = 0; e < 4; ++e) {
            const unsigned u = __float_as_uint(sv[tid + 256*e]);
            if ((u & pmask) == prefix) atomicAdd(&hist[(u >> shift) & 255u], 1u);
        }
        __syncthreads();
        ssum[tid] = (int)hist[tid];
        __syncthreads();
        for (int off = 1; off < 256; off <<= 1) {
            const int add = (tid + off < 256) ? ssum[tid + off] : 0;
            __syncthreads();
            ssum[tid] += add;
            __syncthreads();
        }
        const int above = (tid < 255) ? ssum[tid + 1] : 0;
        if (ssum[tid] >= krem && above < krem) {
            sc[0] = (unsigned)tid;
            sc[1] = (unsigned)(krem - above);
        }
        __syncthreads();
        prefix |= sc[0] << shift;
        pmask |= 0xFFu << shift;
        krem = (int)sc[1];
        __syncthreads();
    }
    const unsigned T = prefix;
    const int m = krem;   // ties at T: lowest indices first (jax top_k order)

    #pragma unroll
    for (int e = 0; e < 4; ++e) {
        const int i = tid + 256*e;
        const float v = sv[i];
        const unsigned u = __float_as_uint(v);
        bool sel = (u > T);
        if (!sel && u == T) {
            int rank = 0;
            for (int j = 0; j < i; ++j) rank += (__float_as_uint(sv[j]) == T) ? 1 : 0;
            sel = (rank < m);
        }
        if (sel) {
            const unsigned p = atomicAdd(&sc[2], 1u);
            if (p < 104u) { sel_v[p] = v; sel_i[p] = i; }
        }
    }
    __syncthreads();

    rbuf[tid] = (tid < KTOP) ? sel_v[tid] : 0.f;
    __syncthreads();
    for (int st = 128; st > 0; st >>= 1) { if (tid < st) rbuf[tid] += rbuf[tid + st]; __syncthreads(); }
    const float sumtop = rbuf[0];
    __syncthreads();
    rbuf[tid] = (tid < KTOP) ? sel_v[tid] : -1.f;
    __syncthreads();
    for (int st = 128; st > 0; st >>= 1) { if (tid < st) rbuf[tid] = fmaxf(rbuf[tid], rbuf[tid + st]); __syncthreads(); }
    const float vmax = rbuf[0];
    __syncthreads();

    const float S_row = RS[(h << 10) + n];
    const float denom = sumtop + 1e-8f * S_row;    // == (sum tp + 1e-8) * S_row
    const float scl = (float)KTOP / denom;
    if (tid < KTOP) sel_w[tid] = expf(sel_v[tid] * scl - vmax * scl);
    __syncthreads();
    rbuf[tid] = (tid < KTOP) ? sel_w[tid] : 0.f;
    __syncthreads();
    for (int st = 128; st > 0; st >>= 1) { if (tid < st) rbuf[tid] += rbuf[tid + st]; __syncthreads(); }
    const float Z = rbuf[0];
    __syncthreads();

    if (tid < 128) {
        const int d = tid & 63;
        const int im = tid >> 6;
        const float* Vp = im ? Vim : Vre;
        const int base = h * 64 + d;
        float acc = 0.f;
        for (int j = 0; j < KTOP; ++j) acc += sel_w[j] * Vp[(size_t)sel_i[j] * 512 + base];
        acc /= Z;
        float* AOp = im ? AOim : AOre;
        AOp[(size_t)n * 512 + h * 64 + d] = acc;
    }
}

// planar copy [Yre|Yim] -> d_out, bounded by out_size floats (R10/R11 rule!)
__launch_bounds__(256)
__global__ void copy_out_kernel(const float* __restrict__ Y,
                                float* __restrict__ out, int out_floats)
{
    const int i = blockIdx.x * 256 + threadIdx.x;   // < 1048576
    if (i < out_floats && i < 2*PPLANE) out[i] = Y[i];
}

// ---------------------------------------------------------------------------
extern "C" void kernel_launch(void* const* d_in, const int* in_sizes, int n_in,
                              void* d_out, int out_size, void* d_ws, size_t ws_size,
                              hipStream_t stream)
{
    (void)in_sizes; (void)n_in; (void)d_ws; (void)ws_size;
    const float* x_re = (const float*)d_in[0];
    const float* x_im = (const float*)d_in[1];
    // d_in[10..13] (phase MLP) are dead code.

    float* pool = nullptr;
    hipGetSymbolAddress((void**)&pool, HIP_SYMBOL(g_pool));   // query only; capture-safe

    float* Wall = pool;                // 4 complex 512^2: [W0re|W0im|W1re|...]
    float* RSg  = Wall + 4*CMAT;       // 8192 row sums (8 heads x 1024)
    float* R    = RSg + 8192;          // union region: R_FLOATS
    // Phase A (all 4 weights batched): 6 buffers x 4 weights x CMAT
    float* A  = R;
    float* S  = R + 4*CMAT;
    float* S2 = R + 8*CMAT;
    float* X  = R + 12*CMAT;           // U, then X0, then NS ping
    float* X2 = R + 16*CMAT;           // V, then NS pong
    float* T  = R + 20*CMAT;           // NS temp, then P
    // Phase B (overlays the same region):
    float* Q  = R;                     // CPROJ floats each
    float* Kp = R + CPROJ;
    float* V  = R + 2*CPROJ;
    float* AO = R + 3*CPROJ;
    float* B2 = R + 4*CPROJ;           // 8 x 1024x1024; later reused as Y

    const int aoff = (int)(A - pool);

    // ---- Phase A: Cayley unitaries, all 4 weights per dispatch (z=4) ----
    build_A_kernel<<<dim3(1024,4),256,0,stream>>>(
        (const float*)d_in[2],(const float*)d_in[3],(const float*)d_in[4],(const float*)d_in[5],
        (const float*)d_in[6],(const float*)d_in[7],(const float*)d_in[8],(const float*)d_in[9], aoff);
    // S = A*A
    cgemm_kernel<<<dim3(8,16,4),256,0,stream>>>(A,A+PLANE,CMAT, A,A+PLANE,CMAT,
                                                A,A+PLANE,CMAT, S,S+PLANE,CMAT,
                                                512,512,512, 0.f,0);
    // S2 = S*S
    cgemm_kernel<<<dim3(8,16,4),256,0,stream>>>(S,S+PLANE,CMAT, S,S+PLANE,CMAT,
                                                S,S+PLANE,CMAT, S2,S2+PLANE,CMAT,
                                                512,512,512, 0.f,0);
    // U = 5.5 S + 0.5 S2  (into X slot)
    u_kernel<<<dim3(2048,4),256,0,stream>>>(S, S2, X);
    // V = S2*U  (into X2 slot)
    cgemm_kernel<<<dim3(8,16,4),256,0,stream>>>(S2,S2+PLANE,CMAT, X,X+PLANE,CMAT,
                                                S2,S2+PLANE,CMAT, X2,X2+PLANE,CMAT,
                                                512,512,512, 0.f,0);
    // X0 = (60.5 I + 48 S + 23 S2 + V)/61.5  (overwrites U in X)
    x0deg4_kernel<<<dim3(1024,4),256,0,stream>>>(S, S2, X2, X);
    // 2 Newton-Schulz iterations: X <- X(2I - B X), B = I - S
    float* Xc = X; float* Xn = X2;
    for (int it = 0; it < 2; ++it) {
        // T = B*X = X - S*X
        cgemm_kernel<<<dim3(8,16,4),256,0,stream>>>(S,S+PLANE,CMAT, Xc,Xc+PLANE,CMAT,
                                                    Xc,Xc+PLANE,CMAT, T,T+PLANE,CMAT,
                                                    512,512,512, 1.f,1);
        // Xn = 2X - X*T
        cgemm_kernel<<<dim3(8,16,4),256,0,stream>>>(Xc,Xc+PLANE,CMAT, T,T+PLANE,CMAT,
                                                    Xc,Xc+PLANE,CMAT, Xn,Xn+PLANE,CMAT,
                                                    512,512,512, 2.f,1);
        float* tmp = Xc; Xc = Xn; Xn = tmp;
    }
    buildP_kernel<<<dim3(1024,4),256,0,stream>>>(A, S, T);   // T = I + 2A + S
    cgemm_kernel<<<dim3(8,16,4),256,0,stream>>>(T,T+PLANE,CMAT, Xc,Xc+PLANE,CMAT,
                                                T,T+PLANE,CMAT, Wall,Wall+PLANE,CMAT,
                                                512,512,512, 0.f,0);

    // ---- Phase B: projections Q,K,V = x @ W[0..2] (batched z=3) ----
    cgemm_kernel<<<dim3(8,32,3),256,0,stream>>>(x_re,x_im,0, Wall,Wall+PLANE,CMAT,
                                                x_re,x_im,0, Q,Q+PPLANE,CPROJ,
                                                1024,512,512, 0.f,0);

    zero_kernel<<<32,256,0,stream>>>(RSg, 8192);
    scores_kernel<<<dim3(16,16,8),256,0,stream>>>(Q,Q+PPLANE, Kp,Kp+PPLANE, B2, RSg);
    select_kernel<<<8192,256,0,stream>>>(B2, RSg, V,V+PPLANE, AO,AO+PPLANE);

    // ---- Output projection into Y (=B2 region, dead now), then bounded copy ----
    float* Y = B2;
    cgemm_kernel<<<dim3(8,32,1),256,0,stream>>>(AO,AO+PPLANE,0, Wall+3*CMAT,Wall+3*CMAT+PLANE,0,
                                                AO,AO+PPLANE,0, Y,Y+PPLANE,0,
                                                1024,512,512, 0.f,0);
    copy_out_kernel<<<4096,256,0,stream>>>(Y, (float*)d_out, out_size);
}

// Round 15
// 1012.459 us; speedup vs baseline: 1.0623x; 1.0623x over previous
//
#include <hip/hip_runtime.h>
#include <math.h>

// ---------------------------------------------------------------------------
// QuantumSuperpositionAttention  (B=1, N=1024, DIM=512, H=8, DH=64, k=102)
//
// Identities:
//  * phase MLP is dead code: |alpha * e^{i phi}|^2 == |alpha|^2
//  * cayley(M): A = 0.02*((Mre - Mre^T) + i(Mim + Mim^T));
//    W = (I-A)^{-1}(I+A) = 2(I-A)^{-1} - I = 2(I+A)X - I,  X = inv(B),
//    B = I - A^2 Hermitian PD, spec [1,5).
//  * inv(B): deg-4 minimax init (PS form) + 2 NS -> rho ~ 7e-8 < fp32 floor.
//  * GEMM CORE LESSON (R9/R13/R14): 32x64/2x4/BK=32 LDS kernel is the local
//    optimum (~55% VALU); split-K, tri-skip, direct-global-A all equal/worse.
//  * ACCURACY RULES (R7/R9): W error at fp32 floor; never change summation
//    ORDER in the Wq/Wk/Q/K/scores chain. Floor-scale W REALIZATION changes
//    are safe (R6/R8/R12/R13: all exactly 1 bf16 ulp).
//  * D_OUT BOUNDS RULE (R10/R11): d_out holds exactly out_size floats; every
//    d_out store is bounds-checked (mode 5 epilogue = old copy_out semantics).
//
// R15: revert cgemm core to R12; fuse u/x0deg4/buildP/copy_out into GEMM
// epilogue modes (-4 dispatches): mode2 S2+U, mode3 X0, mode4 W=2X+2AX-I,
// mode5 bounded scalar d_out store.
// ---------------------------------------------------------------------------

#define PLANE   262144      // 512*512
#define CMAT    524288      // floats per complex 512x512 (2 MB)
#define PPLANE  524288      // 1024*512
#define CPROJ   1048576     // floats per complex 1024x512 (4 MB)
#define KTOP    102

#define R_FLOATS 12582912
#define POOL_FLOATS (4*CMAT + 8192 + R_FLOATS)
__device__ __attribute__((aligned(256))) float g_pool[POOL_FLOATS];

// ---------------------------------------------------------------------------
// Complex planar GEMM, R12 core: 32x64 C-tile / 256 thr / 2x4 microtile /
// BK=32. Grid (N/64, M/32, batch). Epilogue modes:
//  0: C = A*B
//  1: C = dcoef*D - A*B                       (NS steps)
//  2: C = A*B (=S2);  E = 5.5*D + 0.5*C      (D=S, E=U)
//  3: C = (60.5*I + 48*D + 23*E + A*B)/61.5  (D=S, E=S2; C=X0)
//  4: C = 2*D + 2*A*B - I                    (D=X; C=W)
//  5: C = A*B, scalar stores bounded by out_floats; im plane at +PPLANE
// ---------------------------------------------------------------------------
__launch_bounds__(256)
__global__ void cgemm_kernel(
    const float* __restrict__ Are, const float* __restrict__ Aim, int sA,
    const float* __restrict__ Bre, const float* __restrict__ Bim, int sB,
    const float* __restrict__ Dre, const float* __restrict__ Dim, int sD,
    const float* __restrict__ Ere2, float* __restrict__ Ewr, int sE,
    float* __restrict__ Cre, float* __restrict__ Cim, int sC,
    int M, int N, int Kd, float dcoef, int mode, int out_floats)
{
    __shared__ float As_re[32][34], As_im[32][34];
    __shared__ float Bs_re[32][68], Bs_im[32][68];
    const int b = blockIdx.z;
    Are += (size_t)b * sA; Aim += (size_t)b * sA;
    Bre += (size_t)b * sB; Bim += (size_t)b * sB;
    Dre += (size_t)b * sD; Dim += (size_t)b * sD;
    const float* Ere = Ere2 + (size_t)b * sE;
    const float* Eim = Ere + PLANE;      // E input (S2) planes
    float* Uwr = Ewr ? (Ewr + (size_t)b * sE) : (float*)0;
    Cre += (size_t)b * sC; Cim += (size_t)b * sC;
    const int tid = threadIdx.x;
    const int bm = blockIdx.y * 32, bn = blockIdx.x * 64;
    const int tm = (tid >> 4) << 1;      // 0..30 (2 rows)
    const int tn = (tid & 15) << 2;      // 0..60 (4 cols)
    const int lmA = tid >> 3;            // 0..31
    const int lkA = (tid & 7) << 2;      // 0,4..28
    const int lkB = tid >> 4;            // 0..15
    const int lnB = (tid & 15) << 2;     // 0..60
    float cr[2][4] = {{0.f}}, ci[2][4] = {{0.f}};
    const float* pAre = Are + (size_t)(bm + lmA) * Kd + lkA;
    const float* pAim = Aim + (size_t)(bm + lmA) * Kd + lkA;
    const float* pBre = Bre + (size_t)lkB * N + bn + lnB;
    const float* pBim = Bim + (size_t)lkB * N + bn + lnB;
    for (int k0 = 0; k0 < Kd; k0 += 32) {
        const float4 ar = *(const float4*)(pAre + k0);
        const float4 ai = *(const float4*)(pAim + k0);
        const float4 br0 = *(const float4*)(pBre + (size_t)k0 * N);
        const float4 bi0 = *(const float4*)(pBim + (size_t)k0 * N);
        const float4 br1 = *(const float4*)(pBre + (size_t)(k0 + 16) * N);
        const float4 bi1 = *(const float4*)(pBim + (size_t)(k0 + 16) * N);
        __syncthreads();
        As_re[lkA+0][lmA] = ar.x; As_re[lkA+1][lmA] = ar.y;
        As_re[lkA+2][lmA] = ar.z; As_re[lkA+3][lmA] = ar.w;
        As_im[lkA+0][lmA] = ai.x; As_im[lkA+1][lmA] = ai.y;
        As_im[lkA+2][lmA] = ai.z; As_im[lkA+3][lmA] = ai.w;
        *(float4*)&Bs_re[lkB][lnB] = br0;
        *(float4*)&Bs_im[lkB][lnB] = bi0;
        *(float4*)&Bs_re[lkB+16][lnB] = br1;
        *(float4*)&Bs_im[lkB+16][lnB] = bi1;
        __syncthreads();
        #pragma unroll
        for (int k = 0; k < 32; ++k) {
            const float2 xr = *(const float2*)&As_re[k][tm];
            const float2 xi = *(const float2*)&As_im[k][tm];
            const float4 yr = *(const float4*)&Bs_re[k][tn];
            const float4 yi = *(const float4*)&Bs_im[k][tn];
            const float axr[2] = {xr.x, xr.y};
            const float axi[2] = {xi.x, xi.y};
            const float byr[4] = {yr.x, yr.y, yr.z, yr.w};
            const float byi[4] = {yi.x, yi.y, yi.z, yi.w};
            #pragma unroll
            for (int i = 0; i < 2; ++i) {
                #pragma unroll
                for (int j = 0; j < 4; ++j) {
                    cr[i][j] += axr[i]*byr[j] - axi[i]*byi[j];
                    ci[i][j] += axr[i]*byi[j] + axi[i]*byr[j];
                }
            }
        }
    }
    #pragma unroll
    for (int i = 0; i < 2; ++i) {
        const int row = bm + tm + i;
        const size_t idx = (size_t)row * N + bn + tn;
        float vr[4] = {cr[i][0], cr[i][1], cr[i][2], cr[i][3]};
        float vi[4] = {ci[i][0], ci[i][1], ci[i][2], ci[i][3]};
        if (mode == 1) {
            const float4 dr4 = *(const float4*)(Dre + idx);
            const float4 di4 = *(const float4*)(Dim + idx);
            const float dr[4] = {dr4.x, dr4.y, dr4.z, dr4.w};
            const float di[4] = {di4.x, di4.y, di4.z, di4.w};
            #pragma unroll
            for (int j = 0; j < 4; ++j) { vr[j] = dcoef*dr[j] - vr[j]; vi[j] = dcoef*di[j] - vi[j]; }
        } else if (mode == 2) {
            const float4 dr4 = *(const float4*)(Dre + idx);
            const float4 di4 = *(const float4*)(Dim + idx);
            const float dr[4] = {dr4.x, dr4.y, dr4.z, dr4.w};
            const float di[4] = {di4.x, di4.y, di4.z, di4.w};
            float ur[4], ui[4];
            #pragma unroll
            for (int j = 0; j < 4; ++j) { ur[j] = 5.5f*dr[j] + 0.5f*vr[j]; ui[j] = 5.5f*di[j] + 0.5f*vi[j]; }
            *(float4*)(Uwr + idx) = make_float4(ur[0], ur[1], ur[2], ur[3]);
            *(float4*)(Uwr + PLANE + idx) = make_float4(ui[0], ui[1], ui[2], ui[3]);
        } else if (mode == 3) {
            const float inv61 = 1.0f/61.5f;
            const float4 sr4 = *(const float4*)(Dre + idx);
            const float4 si4 = *(const float4*)(Dim + idx);
            const float4 s2r = *(const float4*)(Ere + idx);
            const float4 s2i = *(const float4*)(Eim + idx);
            const float sr[4] = {sr4.x, sr4.y, sr4.z, sr4.w};
            const float si[4] = {si4.x, si4.y, si4.z, si4.w};
            const float tr[4] = {s2r.x, s2r.y, s2r.z, s2r.w};
            const float ti[4] = {s2i.x, s2i.y, s2i.z, s2i.w};
            #pragma unroll
            for (int j = 0; j < 4; ++j) {
                const float diag = (row == bn + tn + j) ? 60.5f : 0.0f;
                vr[j] = (diag + 48.f*sr[j] + 23.f*tr[j] + vr[j]) * inv61;
                vi[j] = (       48.f*si[j] + 23.f*ti[j] + vi[j]) * inv61;
            }
        } else if (mode == 4) {
            const float4 dr4 = *(const float4*)(Dre + idx);
            const float4 di4 = *(const float4*)(Dim + idx);
            const float dr[4] = {dr4.x, dr4.y, dr4.z, dr4.w};
            const float di[4] = {di4.x, di4.y, di4.z, di4.w};
            #pragma unroll
            for (int j = 0; j < 4; ++j) {
                const float diag = (row == bn + tn + j) ? 1.0f : 0.0f;
                vr[j] = 2.f*dr[j] + 2.f*vr[j] - diag;
                vi[j] = 2.f*di[j] + 2.f*vi[j];
            }
        }
        if (mode == 5) {
            // bounded scalar stores straight to d_out (copy_out semantics)
            #pragma unroll
            for (int j = 0; j < 4; ++j) {
                const size_t ire = idx + j;
                const size_t iim = (size_t)PPLANE + idx + j;
                if (ire < (size_t)out_floats) Cre[ire] = vr[j];
                if (iim < (size_t)out_floats) Cre[iim] = vi[j];
            }
        } else {
            *(float4*)(Cre + idx) = make_float4(vr[0], vr[1], vr[2], vr[3]);
            *(float4*)(Cim + idx) = make_float4(vi[0], vi[1], vi[2], vi[3]);
        }
    }
}

// A = 0.02*((Mre - Mre^T) + i(Mim + Mim^T)) for all 4 weights (blockIdx.y).
__launch_bounds__(256)
__global__ void build_A_kernel(const float* __restrict__ W0re, const float* __restrict__ W0im,
                               const float* __restrict__ W1re, const float* __restrict__ W1im,
                               const float* __restrict__ W2re, const float* __restrict__ W2im,
                               const float* __restrict__ W3re, const float* __restrict__ W3im,
                               int aoff)
{
    float* Aout = g_pool + aoff;
    const int w = blockIdx.y;
    const float* Mre; const float* Mim;
    if      (w == 0) { Mre = W0re; Mim = W0im; }
    else if (w == 1) { Mre = W1re; Mim = W1im; }
    else if (w == 2) { Mre = W2re; Mim = W2im; }
    else             { Mre = W3re; Mim = W3im; }
    const int idx = blockIdx.x * 256 + threadIdx.x;   // < 262144
    const int i = idx >> 9, j = idx & 511;
    float* Are = Aout + (size_t)w * CMAT;
    float* Aim = Are + PLANE;
    Are[idx] = 0.02f * (Mre[i*512 + j] - Mre[j*512 + i]);
    Aim[idx] = 0.02f * (Mim[i*512 + j] + Mim[j*512 + i]);
}

__launch_bounds__(256)
__global__ void zero_kernel(float* __restrict__ p, int n)
{
    const int i = blockIdx.x * 256 + threadIdx.x;
    if (i < n) p[i] = 0.f;
}

// All heads: b2[h,n,s] = |conj(Q[n,h,:]) . K[s,h,:]|^2 * SCALE^2, + row sums.
__launch_bounds__(256)
__global__ void scores_kernel(const float* __restrict__ Qre, const float* __restrict__ Qim,
                              const float* __restrict__ Kre, const float* __restrict__ Kim,
                              float* __restrict__ B2, float* __restrict__ RS)
{
    __shared__ float Qs_re[16][68], Qs_im[16][68], Ks_re[16][68], Ks_im[16][68];
    __shared__ float rs[64];
    const int h = blockIdx.z;
    const int bm = blockIdx.y * 64, bn = blockIdx.x * 64;
    const int tid = threadIdx.x;
    const int tm = (tid >> 4) << 2, tn = (tid & 15) << 2;
    const int lm = tid >> 2, lk = (tid & 3) << 2;
    float dr[4][4] = {{0.f}}, di[4][4] = {{0.f}};
    for (int k0 = 0; k0 < 64; k0 += 16) {
        const float4 qr = *(const float4*)(Qre + (size_t)(bm+lm)*512 + h*64 + k0 + lk);
        const float4 qi = *(const float4*)(Qim + (size_t)(bm+lm)*512 + h*64 + k0 + lk);
        const float4 kr = *(const float4*)(Kre + (size_t)(bn+lm)*512 + h*64 + k0 + lk);
        const float4 ki = *(const float4*)(Kim + (size_t)(bn+lm)*512 + h*64 + k0 + lk);
        __syncthreads();
        Qs_re[lk+0][lm]=qr.x; Qs_re[lk+1][lm]=qr.y; Qs_re[lk+2][lm]=qr.z; Qs_re[lk+3][lm]=qr.w;
        Qs_im[lk+0][lm]=qi.x; Qs_im[lk+1][lm]=qi.y; Qs_im[lk+2][lm]=qi.z; Qs_im[lk+3][lm]=qi.w;
        Ks_re[lk+0][lm]=kr.x; Ks_re[lk+1][lm]=kr.y; Ks_re[lk+2][lm]=kr.z; Ks_re[lk+3][lm]=kr.w;
        Ks_im[lk+0][lm]=ki.x; Ks_im[lk+1][lm]=ki.y; Ks_im[lk+2][lm]=ki.z; Ks_im[lk+3][lm]=ki.w;
        __syncthreads();
        #pragma unroll
        for (int k = 0; k < 16; ++k) {
            const float4 xr = *(const float4*)&Qs_re[k][tm];
            const float4 xi = *(const float4*)&Qs_im[k][tm];
            const float4 yr = *(const float4*)&Ks_re[k][tn];
            const float4 yi = *(const float4*)&Ks_im[k][tn];
            const float axr[4] = {xr.x, xr.y, xr.z, xr.w};
            const float axi[4] = {xi.x, xi.y, xi.z, xi.w};
            const float byr[4] = {yr.x, yr.y, yr.z, yr.w};
            const float byi[4] = {yi.x, yi.y, yi.z, yi.w};
            #pragma unroll
            for (int i = 0; i < 4; ++i) {
                #pragma unroll
                for (int j = 0; j < 4; ++j) {
                    dr[i][j] += axr[i]*byr[j] + axi[i]*byi[j];   // re(conj(q)*k)
                    di[i][j] += axr[i]*byi[j] - axi[i]*byr[j];   // im(conj(q)*k)
                }
            }
        }
    }
    if (tid < 64) rs[tid] = 0.f;
    __syncthreads();
    float rpart[4] = {0.f, 0.f, 0.f, 0.f};
    #pragma unroll
    for (int i = 0; i < 4; ++i) {
        #pragma unroll
        for (int j = 0; j < 4; ++j) {
            const float b2v = (dr[i][j]*dr[i][j] + di[i][j]*di[i][j]) * 0.015625f;
            B2[(size_t)h*1048576 + (size_t)(bm+tm+i)*1024 + (bn+tn+j)] = b2v;
            rpart[i] += b2v;
        }
    }
    #pragma unroll
    for (int i = 0; i < 4; ++i) atomicAdd(&rs[tm+i], rpart[i]);
    __syncthreads();
    if (tid < 64) atomicAdd(&RS[h*1024 + bm + tid], rs[tid]);
}

// Per (h,n) row: exact top-102 radix select, softmax, weighted V gather.
__launch_bounds__(256)
__global__ void select_kernel(const float* __restrict__ B2, const float* __restrict__ RS,
                              const float* __restrict__ Vre, const float* __restrict__ Vim,
                              float* __restrict__ AOre, float* __restrict__ AOim)
{
    __shared__ float sv[1024];
    __shared__ unsigned int hist[256];
    __shared__ int ssum[256];
    __shared__ unsigned int sc[4];
    __shared__ float sel_v[104];
    __shared__ int sel_i[104];
    __shared__ float sel_w[104];
    __shared__ float rbuf[256];
    const int bid = blockIdx.x;
    const int h = bid >> 10, n = bid & 1023;
    const int tid = threadIdx.x;
    const float* row = B2 + (size_t)h * 1048576 + (size_t)n * 1024;
    #pragma unroll
    for (int e = 0; e < 4; ++e) sv[tid + 256*e] = row[tid + 256*e];
    if (tid == 0) sc[2] = 0u;
    __syncthreads();

    unsigned prefix = 0u, pmask = 0u;
    int krem = KTOP;
    for (int pass = 0; pass < 4; ++pass) {
        const int shift = 24 - 8 * pass;
        hist[tid] = 0u;
        __syncthreads();
        #pragma unroll
        for (int e = 0; e < 4; ++e) {
            const unsigned u = __float_as_uint(sv[tid + 256*e]);
            if ((u & pmask) == prefix) atomicAdd(&hist[(u >> shift) & 255u], 1u);
        }
        __syncthreads();
        ssum[tid] = (int)hist[tid];
        __syncthreads();
        for (int off = 1; off < 256; off <<= 1) {
            const int add = (tid + off < 256) ? ssum[tid + off] : 0;
            __syncthreads();
            ssum[tid] += add;
            __syncthreads();
        }
        const int above = (tid < 255) ? ssum[tid + 1] : 0;
        if (ssum[tid] >= krem && above < krem) {
            sc[0] = (unsigned)tid;
            sc[1] = (unsigned)(krem - above);
        }
        __syncthreads();
        prefix |= sc[0] << shift;
        pmask |= 0xFFu << shift;
        krem = (int)sc[1];
        __syncthreads();
    }
    const unsigned T = prefix;
    const int m = krem;   // ties at T: lowest indices first (jax top_k order)

    #pragma unroll
    for (int e = 0; e < 4; ++e) {
        const int i = tid + 256*e;
        const float v = sv[i];
        const unsigned u = __float_as_uint(v);
        bool sel = (u > T);
        if (!sel && u == T) {
            int rank = 0;
            for (int j = 0; j < i; ++j) rank += (__float_as_uint(sv[j]) == T) ? 1 : 0;
            sel = (rank < m);
        }
        if (sel) {
            const unsigned p = atomicAdd(&sc[2], 1u);
            if (p < 104u) { sel_v[p] = v; sel_i[p] = i; }
        }
    }
    __syncthreads();

    rbuf[tid] = (tid < KTOP) ? sel_v[tid] : 0.f;
    __syncthreads();
    for (int st = 128; st > 0; st >>= 1) { if (tid < st) rbuf[tid] += rbuf[tid + st]; __syncthreads(); }
    const float sumtop = rbuf[0];
    __syncthreads();
    rbuf[tid] = (tid < KTOP) ? sel_v[tid] : -1.f;
    __syncthreads();
    for (int st = 128; st > 0; st >>= 1) { if (tid < st) rbuf[tid] = fmaxf(rbuf[tid], rbuf[tid + st]); __syncthreads(); }
    const float vmax = rbuf[0];
    __syncthreads();

    const float S_row = RS[(h << 10) + n];
    const float denom = sumtop + 1e-8f * S_row;    // == (sum tp + 1e-8) * S_row
    const float scl = (float)KTOP / denom;
    if (tid < KTOP) sel_w[tid] = expf(sel_v[tid] * scl - vmax * scl);
    __syncthreads();
    rbuf[tid] = (tid < KTOP) ? sel_w[tid] : 0.f;
    __syncthreads();
    for (int st = 128; st > 0; st >>= 1) { if (tid < st) rbuf[tid] += rbuf[tid + st]; __syncthreads(); }
    const float Z = rbuf[0];
    __syncthreads();

    if (tid < 128) {
        const int d = tid & 63;
        const int im = tid >> 6;
        const float* Vp = im ? Vim : Vre;
        const int base = h * 64 + d;
        float acc = 0.f;
        for (int j = 0; j < KTOP; ++j) acc += sel_w[j] * Vp[(size_t)sel_i[j] * 512 + base];
        acc /= Z;
        float* AOp = im ? AOim : AOre;
        AOp[(size_t)n * 512 + h * 64 + d] = acc;
    }
}

// ---------------------------------------------------------------------------
extern "C" void kernel_launch(void* const* d_in, const int* in_sizes, int n_in,
                              void* d_out, int out_size, void* d_ws, size_t ws_size,
                              hipStream_t stream)
{
    (void)in_sizes; (void)n_in; (void)d_ws; (void)ws_size;
    const float* x_re = (const float*)d_in[0];
    const float* x_im = (const float*)d_in[1];
    // d_in[10..13] (phase MLP) are dead code.

    float* pool = nullptr;
    hipGetSymbolAddress((void**)&pool, HIP_SYMBOL(g_pool));   // query only; capture-safe

    float* Wall = pool;                // 4 complex 512^2: [W0re|W0im|W1re|...]
    float* RSg  = Wall + 4*CMAT;       // 8192 row sums (8 heads x 1024)
    float* R    = RSg + 8192;          // union region
    // Phase A (all 4 weights batched): 6 buffers x 4 weights x CMAT
    float* A  = R;
    float* S  = R + 4*CMAT;
    float* S2 = R + 8*CMAT;
    float* X  = R + 12*CMAT;           // U, then NS ping
    float* X2 = R + 16*CMAT;           // X0, then NS pong
    float* T  = R + 20*CMAT;           // NS temp
    // Phase B (overlays the same region):
    float* Q  = R;                     // CPROJ floats each
    float* Kp = R + CPROJ;
    float* V  = R + 2*CPROJ;
    float* AO = R + 3*CPROJ;
    float* B2 = R + 4*CPROJ;           // 8 x 1024x1024

    const int aoff = (int)(A - pool);

    // ---- Phase A: Cayley unitaries, all 4 weights per dispatch (z=4) ----
    build_A_kernel<<<dim3(1024,4),256,0,stream>>>(
        (const float*)d_in[2],(const float*)d_in[3],(const float*)d_in[4],(const float*)d_in[5],
        (const float*)d_in[6],(const float*)d_in[7],(const float*)d_in[8],(const float*)d_in[9], aoff);
    // S = A*A   (mode 0)
    cgemm_kernel<<<dim3(8,16,4),256,0,stream>>>(A,A+PLANE,CMAT, A,A+PLANE,CMAT,
                                                A,A+PLANE,CMAT, A,nullptr,CMAT,
                                                S,S+PLANE,CMAT, 512,512,512, 0.f, 0, 0);
    // S2 = S*S; U = 5.5 S + 0.5 S2 -> X slot  (mode 2, D=S, Ewr=X)
    cgemm_kernel<<<dim3(8,16,4),256,0,stream>>>(S,S+PLANE,CMAT, S,S+PLANE,CMAT,
                                                S,S+PLANE,CMAT, S,X,CMAT,
                                                S2,S2+PLANE,CMAT, 512,512,512, 0.f, 2, 0);
    // X0 = (60.5 I + 48 S + 23 S2 + S2*U)/61.5 -> X2  (mode 3, D=S, E=S2)
    cgemm_kernel<<<dim3(8,16,4),256,0,stream>>>(S2,S2+PLANE,CMAT, X,X+PLANE,CMAT,
                                                S,S+PLANE,CMAT, S2,nullptr,CMAT,
                                                X2,X2+PLANE,CMAT, 512,512,512, 0.f, 3, 0);
    // 2 Newton-Schulz iterations: X <- X(2I - B X), B = I - S
    float* Xc = X2; float* Xn = X;     // X0 lives in X2; X slot (U) is dead
    for (int it = 0; it < 2; ++it) {
        // T = 1*X - S*X  (mode 1)
        cgemm_kernel<<<dim3(8,16,4),256,0,stream>>>(S,S+PLANE,CMAT, Xc,Xc+PLANE,CMAT,
                                                    Xc,Xc+PLANE,CMAT, S,nullptr,CMAT,
                                                    T,T+PLANE,CMAT, 512,512,512, 1.f, 1, 0);
        // Xn = 2*X - X*T  (mode 1)
        cgemm_kernel<<<dim3(8,16,4),256,0,stream>>>(Xc,Xc+PLANE,CMAT, T,T+PLANE,CMAT,
                                                    Xc,Xc+PLANE,CMAT, S,nullptr,CMAT,
                                                    Xn,Xn+PLANE,CMAT, 512,512,512, 2.f, 1, 0);
        float* tmp = Xc; Xc = Xn; Xn = tmp;
    }
    // W = 2X + 2*A*X - I  (mode 4, D=X) -> Wall   [= (I-A)^{-1}(I+A)]
    cgemm_kernel<<<dim3(8,16,4),256,0,stream>>>(A,A+PLANE,CMAT, Xc,Xc+PLANE,CMAT,
                                                Xc,Xc+PLANE,CMAT, S,nullptr,CMAT,
                                                Wall,Wall+PLANE,CMAT, 512,512,512, 0.f, 4, 0);

    // ---- Phase B: projections Q,K,V = x @ W[0..2] (batched z=3, mode 0) ----
    cgemm_kernel<<<dim3(8,32,3),256,0,stream>>>(x_re,x_im,0, Wall,Wall+PLANE,CMAT,
                                                x_re,x_im,0, S,nullptr,0,
                                                Q,Q+PPLANE,CPROJ, 1024,512,512, 0.f, 0, 0);

    zero_kernel<<<32,256,0,stream>>>(RSg, 8192);
    scores_kernel<<<dim3(16,16,8),256,0,stream>>>(Q,Q+PPLANE, Kp,Kp+PPLANE, B2, RSg);
    select_kernel<<<8192,256,0,stream>>>(B2, RSg, V,V+PPLANE, AO,AO+PPLANE);

    // ---- Output projection straight to d_out (mode 5: bounded scalar) ----
    cgemm_kernel<<<dim3(8,32,1),256,0,stream>>>(AO,AO+PPLANE,0, Wall+3*CMAT,Wall+3*CMAT+PLANE,0,
                                                AO,AO+PPLANE,0, S,nullptr,0,
                                                (float*)d_out,nullptr,0, 1024,512,512, 0.f, 5, out_size);
}